// Round 1
// baseline (11830.183 us; speedup 1.0000x reference)
//
#include <hip/hip_runtime.h>

// MultiModalLSTM on MI355X.
// Decomposition: batch-split, 256 blocks x 16 rows, recurrence block-local
// (no grid sync). Weights streamed bf16 from L2 each step in MFMA-fragment-
// packed layout. State: c in VGPRs (fp32), h in LDS (bf16).

typedef __bf16 bf16x8 __attribute__((ext_vector_type(8)));
typedef float  f32x4  __attribute__((ext_vector_type(4)));

#define NMAT 12
#define MATSZ 262144   // 1024*256
#define BIAS_OFF_BYTES 6291456  // 12*MATSZ*2

__device__ __host__ inline unsigned short f2bf_u(float f){
  union { float f; unsigned u; } v; v.f = f;
  unsigned u = v.u + 0x7fffu + ((v.u >> 16) & 1u);
  return (unsigned short)(u >> 16);
}
__device__ inline float bf2f(unsigned short h){ return __uint_as_float(((unsigned)h) << 16); }
__device__ inline float sigm(float x){ return 1.f / (1.f + __expf(-x)); }
__device__ inline float tanh_(float x){ return 2.f / (1.f + __expf(-2.f * x)) - 1.f; }

struct PrepArgs {
  const float* mats[NMAT];
  const float* ba[8];
  const float* bb[8];
  unsigned short* wp;
  float* bias;
};

// Pack W[1024][256] (row-major fp32) into B-fragment-major bf16:
// packed[((ntile*8 + kk)*64 + lane)*8 + j] = W[ntile*16 + (lane&15)][kk*32 + (lane>>4)*8 + j]
__global__ void prep_kernel(PrepArgs a){
  unsigned i = blockIdx.x * 256u + threadIdx.x;
  if (i < (unsigned)NMAT * MATSZ) {
    unsigned mi = i >> 18;
    unsigned e  = i & (MATSZ - 1u);
    unsigned j  = e & 7u;
    unsigned l  = (e >> 3) & 63u;
    unsigned kk = (e >> 9) & 7u;
    unsigned nt = e >> 12;
    unsigned src = (nt * 16u + (l & 15u)) * 256u + kk * 32u + (l >> 4) * 8u + j;
    a.wp[i] = f2bf_u(a.mats[mi][src]);
  } else if (i < (unsigned)NMAT * MATSZ + 8192u) {
    unsigned e = i - (unsigned)NMAT * MATSZ;
    unsigned cell = e >> 10, n = e & 1023u;
    a.bias[e] = a.ba[cell][n] + a.bb[cell][n];
  }
}

// acc[ut][gt] covers output tile: rows m = (lane>>4)*4 + r, col u = wave*64 + ut*16 + (lane&15),
// gate row in W = gt*256 + u.
__device__ inline void gemm_acc(f32x4 acc[4][4],
                                const unsigned short* __restrict__ Wp,
                                unsigned short (*hb)[264],
                                int wave, int lane){
  const int lr = lane & 15, lg = lane >> 4;
  bf16x8 a[8];
  #pragma unroll
  for (int kk = 0; kk < 8; ++kk)
    a[kk] = *reinterpret_cast<const bf16x8*>(&hb[lr][kk * 32 + lg * 8]);
  #pragma unroll
  for (int ut = 0; ut < 4; ++ut){
    #pragma unroll
    for (int gt = 0; gt < 4; ++gt){
      const int ntile = gt * 16 + wave * 4 + ut;
      const unsigned short* base = Wp + (size_t)ntile * 4096 + (size_t)lane * 8;
      f32x4 c = acc[ut][gt];
      #pragma unroll
      for (int kk = 0; kk < 8; ++kk){
        bf16x8 b = *reinterpret_cast<const bf16x8*>(base + kk * 512);
        c = __builtin_amdgcn_mfma_f32_16x16x32_bf16(a[kk], b, c, 0, 0, 0);
      }
      acc[ut][gt] = c;
    }
  }
}

__device__ inline void acc_bias(f32x4 acc[4][4], const float* __restrict__ bias,
                                int wave, int lane){
  const int lr = lane & 15;
  #pragma unroll
  for (int ut = 0; ut < 4; ++ut){
    const int u = wave * 64 + ut * 16 + lr;
    #pragma unroll
    for (int gt = 0; gt < 4; ++gt){
      const float bb = bias[gt * 256 + u];
      f32x4 v = {bb, bb, bb, bb};
      acc[ut][gt] = v;
    }
  }
}

__device__ inline void acc_xpart(f32x4 acc[4][4], const float* __restrict__ Wih0,
                                 const float xv[4][4], int wave, int lane){
  const int lr = lane & 15;
  #pragma unroll
  for (int ut = 0; ut < 4; ++ut){
    const int u = wave * 64 + ut * 16 + lr;
    #pragma unroll
    for (int gt = 0; gt < 4; ++gt){
      const float4 w = *reinterpret_cast<const float4*>(&Wih0[(gt * 256 + u) * 4]);
      #pragma unroll
      for (int r = 0; r < 4; ++r)
        acc[ut][gt][r] += xv[r][0]*w.x + xv[r][1]*w.y + xv[r][2]*w.z + xv[r][3]*w.w;
    }
  }
}

__device__ inline void acc_dinpart(f32x4 acc[4][4], const float* __restrict__ W2,
                                   const float pv[4][2], int wave, int lane){
  const int lr = lane & 15;
  #pragma unroll
  for (int ut = 0; ut < 4; ++ut){
    const int u = wave * 64 + ut * 16 + lr;
    #pragma unroll
    for (int gt = 0; gt < 4; ++gt){
      const float2 w = *reinterpret_cast<const float2*>(&W2[(gt * 256 + u) * 2]);
      #pragma unroll
      for (int r = 0; r < 4; ++r)
        acc[ut][gt][r] += pv[r][0]*w.x + pv[r][1]*w.y;
    }
  }
}

__device__ inline void cell_update(f32x4 acc[4][4], float cst[4][4],
                                   unsigned short (*hb)[264], int wave, int lane){
  const int lr = lane & 15, lg = lane >> 4;
  #pragma unroll
  for (int ut = 0; ut < 4; ++ut){
    const int u = wave * 64 + ut * 16 + lr;
    #pragma unroll
    for (int r = 0; r < 4; ++r){
      const float gi = acc[ut][0][r], gf = acc[ut][1][r];
      const float gg = acc[ut][2][r], go = acc[ut][3][r];
      float c = sigm(gf) * cst[ut][r] + sigm(gi) * tanh_(gg);
      cst[ut][r] = c;
      hb[lg * 4 + r][u] = f2bf_u(sigm(go) * tanh_(c));
    }
  }
}

__global__ __launch_bounds__(256, 1) void lstm_main(
    const float* __restrict__ x,
    const float* __restrict__ encWih0,
    const float* __restrict__ decWih0,
    const float* __restrict__ headW,
    const float* __restrict__ headB,
    const float* __restrict__ confW,
    const float* __restrict__ confB,
    const unsigned short* __restrict__ wpack,
    const float* __restrict__ bias,
    float* __restrict__ out)
{
  __shared__ float x_loc[16][200];
  __shared__ unsigned short hb0[16][264], hb1[16][264], hs0[16][264], hs1[16][264];
  __shared__ float pin[16][2];

  const int tid = threadIdx.x;
  const int wave = tid >> 6, lane = tid & 63;
  const int lg = lane >> 4;
  const int m0 = blockIdx.x * 16;

  for (int i = tid; i < 16 * 200; i += 256)
    x_loc[i / 200][i % 200] = x[(size_t)(m0 + i / 200) * 200 + (i % 200)];
  for (int i = tid; i < 16 * 264; i += 256){
    (&hb0[0][0])[i] = 0; (&hb1[0][0])[i] = 0;
  }
  float c0[4][4] = {}, c1[4][4] = {};
  __syncthreads();

  const unsigned short* Whh0p = wpack;
  const unsigned short* Wih1p = wpack + MATSZ;
  const unsigned short* Whh1p = wpack + 2 * MATSZ;
  const float* b0 = bias;
  const float* b1 = bias + 1024;

  // ---------------- encoder ----------------
  for (int t = 0; t < 50; ++t){
    f32x4 acc[4][4];
    float xv[4][4];
    #pragma unroll
    for (int r = 0; r < 4; ++r){
      const float4 v = *reinterpret_cast<const float4*>(&x_loc[lg * 4 + r][t * 4]);
      xv[r][0] = v.x; xv[r][1] = v.y; xv[r][2] = v.z; xv[r][3] = v.w;
    }
    acc_bias(acc, b0, wave, lane);
    acc_xpart(acc, encWih0, xv, wave, lane);
    gemm_acc(acc, Whh0p, hb0, wave, lane);
    __syncthreads();
    cell_update(acc, c0, hb0, wave, lane);
    __syncthreads();

    acc_bias(acc, b1, wave, lane);
    gemm_acc(acc, Wih1p, hb0, wave, lane);
    gemm_acc(acc, Whh1p, hb1, wave, lane);
    __syncthreads();
    cell_update(acc, c1, hb1, wave, lane);
    __syncthreads();
  }

  // ---------------- confidence head (uses final h1) ----------------
  if (tid < 16){
    const int m = tid;
    float l3[3];
    #pragma unroll
    for (int j = 0; j < 3; ++j){
      float s = confB[j];
      for (int u = 0; u < 256; ++u) s += bf2f(hb1[m][u]) * confW[j * 256 + u];
      l3[j] = s;
    }
    const float mx = fmaxf(l3[0], fmaxf(l3[1], l3[2]));
    const float e0 = __expf(l3[0] - mx), e1 = __expf(l3[1] - mx), e2 = __expf(l3[2] - mx);
    const float inv = 1.f / (e0 + e1 + e2);
    out[147456 + (size_t)(m0 + m) * 3 + 0] = e0 * inv;
    out[147456 + (size_t)(m0 + m) * 3 + 1] = e1 * inv;
    out[147456 + (size_t)(m0 + m) * 3 + 2] = e2 * inv;
  }

  // save encoder-final state
  for (int i = tid; i < 16 * 264; i += 256){
    (&hs0[0][0])[i] = (&hb0[0][0])[i];
    (&hs1[0][0])[i] = (&hb1[0][0])[i];
  }
  float c0s[4][4], c1s[4][4];
  #pragma unroll
  for (int ut = 0; ut < 4; ++ut)
    #pragma unroll
    for (int r = 0; r < 4; ++r){ c0s[ut][r] = c0[ut][r]; c1s[ut][r] = c1[ut][r]; }
  __syncthreads();

  // ---------------- decoders ----------------
  for (int k = 0; k < 3; ++k){
    for (int i = tid; i < 16 * 264; i += 256){
      (&hb0[0][0])[i] = (&hs0[0][0])[i];
      (&hb1[0][0])[i] = (&hs1[0][0])[i];
    }
    #pragma unroll
    for (int ut = 0; ut < 4; ++ut)
      #pragma unroll
      for (int r = 0; r < 4; ++r){ c0[ut][r] = c0s[ut][r]; c1[ut][r] = c1s[ut][r]; }
    if (tid < 16){ pin[tid][0] = x_loc[tid][196]; pin[tid][1] = x_loc[tid][197]; }
    __syncthreads();

    const unsigned short* dWhh0p = wpack + (size_t)(3 + k) * MATSZ;
    const unsigned short* dWih1p = wpack + (size_t)(6 + k) * MATSZ;
    const unsigned short* dWhh1p = wpack + (size_t)(9 + k) * MATSZ;
    const float* db0 = bias + 2048 + k * 1024;
    const float* db1 = bias + 5120 + k * 1024;
    const float* dW2 = decWih0 + (size_t)k * 2048;

    for (int t = 0; t < 6; ++t){
      f32x4 acc[4][4];
      float pv[4][2];
      #pragma unroll
      for (int r = 0; r < 4; ++r){ pv[r][0] = pin[lg * 4 + r][0]; pv[r][1] = pin[lg * 4 + r][1]; }
      acc_bias(acc, db0, wave, lane);
      acc_dinpart(acc, dW2, pv, wave, lane);
      gemm_acc(acc, dWhh0p, hb0, wave, lane);
      __syncthreads();
      cell_update(acc, c0, hb0, wave, lane);
      __syncthreads();

      acc_bias(acc, db1, wave, lane);
      gemm_acc(acc, dWih1p, hb0, wave, lane);
      gemm_acc(acc, dWhh1p, hb1, wave, lane);
      __syncthreads();
      cell_update(acc, c1, hb1, wave, lane);
      __syncthreads();

      if (tid < 32){
        const int m = tid >> 1, d = tid & 1;
        float s = headB[k * 2 + d];
        const float* hw = headW + (size_t)(k * 2 + d) * 256;
        for (int u = 0; u < 256; ++u) s += bf2f(hb1[m][u]) * hw[u];
        pin[m][d] = s;
        out[(((size_t)(m0 + m) * 3 + k) * 6 + t) * 2 + d] = s;
      }
      __syncthreads();
    }
  }
}

extern "C" void kernel_launch(void* const* d_in, const int* in_sizes, int n_in,
                              void* d_out, int out_size, void* d_ws, size_t ws_size,
                              hipStream_t stream){
  PrepArgs pa;
  pa.mats[0] = (const float*)d_in[2];   // enc_Whh0
  pa.mats[1] = (const float*)d_in[5];   // enc_Wih1
  pa.mats[2] = (const float*)d_in[6];   // enc_Whh1
  for (int k = 0; k < 3; ++k){
    pa.mats[3 + k] = (const float*)d_in[10] + (size_t)k * MATSZ;  // dec_Whh0[k]
    pa.mats[6 + k] = (const float*)d_in[13] + (size_t)k * MATSZ;  // dec_Wih1[k]
    pa.mats[9 + k] = (const float*)d_in[14] + (size_t)k * MATSZ;  // dec_Whh1[k]
  }
  pa.ba[0] = (const float*)d_in[3];  pa.bb[0] = (const float*)d_in[4];   // enc0
  pa.ba[1] = (const float*)d_in[7];  pa.bb[1] = (const float*)d_in[8];   // enc1
  for (int k = 0; k < 3; ++k){
    pa.ba[2 + k] = (const float*)d_in[11] + (size_t)k * 1024;
    pa.bb[2 + k] = (const float*)d_in[12] + (size_t)k * 1024;
    pa.ba[5 + k] = (const float*)d_in[15] + (size_t)k * 1024;
    pa.bb[5 + k] = (const float*)d_in[16] + (size_t)k * 1024;
  }
  pa.wp   = (unsigned short*)d_ws;
  pa.bias = (float*)((char*)d_ws + BIAS_OFF_BYTES);

  prep_kernel<<<12320, 256, 0, stream>>>(pa);

  lstm_main<<<256, 256, 0, stream>>>(
      (const float*)d_in[0],   // x
      (const float*)d_in[1],   // enc_Wih0
      (const float*)d_in[9],   // dec_Wih0
      (const float*)d_in[17],  // head_W
      (const float*)d_in[18],  // head_b
      (const float*)d_in[19],  // conf_W
      (const float*)d_in[20],  // conf_b
      (const unsigned short*)d_ws,
      (const float*)((char*)d_ws + BIAS_OFF_BYTES),
      (float*)d_out);
}

// Round 5
// 2172.041 us; speedup vs baseline: 5.4466x; 5.4466x over previous
//
#include <hip/hip_runtime.h>

// Weight-stationary LSTM, plain launch + per-batch-group scoped-atomic barriers.
// Grid = 16 batch-groups x 16 unit-groups = 256 blocks (1/CU, forced by 103 KB
// LDS). Block owns 64 W-rows (4 gates x 16 units) of each live matrix in LDS.
// h-state in global ping-pong bf16 buffers; c-state in VGPRs.
// Layer skew: each phase computes L0(t) and L1(t-1) -> 1 barrier per step.

typedef __bf16 bf16x8 __attribute__((ext_vector_type(8)));
typedef float  f32x4  __attribute__((ext_vector_type(4)));

#define NMAT 12
#define SLICE_SH 16384                        // shorts per (mat, ug) slice (32 KB)
#define WPACK_SHORTS (NMAT * 16 * SLICE_SH)   // 3,145,728
#define BIAS_OFF_BYTES (WPACK_SHORTS * 2)     // 6,291,456
#define BAR_OFF_BYTES (BIAS_OFF_BYTES + 32768)
#define H_OFF_BYTES (BAR_OFF_BYTES + 4096)
#define HBUF_SHORTS 1048576                   // 4096*256 bf16 = 2 MB

__device__ __host__ inline unsigned short f2bf_u(float f){
  union { float f; unsigned u; } v; v.f = f;
  unsigned u = v.u + 0x7fffu + ((v.u >> 16) & 1u);
  return (unsigned short)(u >> 16);
}
__device__ inline float sigm(float x){ return 1.f / (1.f + __expf(-x)); }
__device__ inline float tanh_(float x){ return 2.f / (1.f + __expf(-2.f * x)) - 1.f; }

struct PrepArgs {
  const float* mats[NMAT];
  const float* ba[8];
  const float* bb[8];
  unsigned short* wp;
  float* bias;
  unsigned* bars;
};

// wpack[mi][ug][g][kk][lane][j] <- W[g*256 + ug*16 + (lane&15)][kk*32 + (lane>>4)*8 + j]
__global__ void prep_kernel(PrepArgs a){
  unsigned i = blockIdx.x * 256u + threadIdx.x;
  if (i < (unsigned)WPACK_SHORTS) {
    unsigned mi = i >> 18;
    unsigned ug = (i >> 14) & 15u;
    unsigned g  = (i >> 12) & 3u;
    unsigned kk = (i >> 9) & 7u;
    unsigned l  = (i >> 3) & 63u;
    unsigned j  = i & 7u;
    unsigned src = (g * 256u + ug * 16u + (l & 15u)) * 256u + kk * 32u + (l >> 4) * 8u + j;
    a.wp[i] = f2bf_u(a.mats[mi][src]);
  } else if (i < (unsigned)WPACK_SHORTS + 8192u) {
    unsigned e = i - (unsigned)WPACK_SHORTS;
    unsigned cell = e >> 10, n = e & 1023u;
    a.bias[e] = a.ba[cell][n] + a.bb[cell][n];
  } else if (i < (unsigned)WPACK_SHORTS + 8192u + 1024u) {
    a.bars[i - (unsigned)WPACK_SHORTS - 8192u] = 0u;  // zero barrier state
  }
}

struct MainArgs {
  const float* x;
  const float* encWih0;
  const float* decWih0;
  const float* headW;
  const float* headB;
  const float* confW;
  const float* confB;
  const unsigned short* wpack;
  const float* bias;
  unsigned* bars;
  unsigned short* hb;   // 6 h-buffers: hp0[2], hp1[2], henc0, henc1
  float* out;
};

// 16-block barrier with proper acquire/release scoped atomics.
// cnt counts cumulatively; barrier #phase complete when cnt == 16*phase.
__device__ inline void bg_barrier(unsigned* cnt, unsigned* gen, unsigned phase){
  __syncthreads();
  if (threadIdx.x == 0){
    unsigned arrived = __hip_atomic_fetch_add(cnt, 1u, __ATOMIC_ACQ_REL,
                                              __HIP_MEMORY_SCOPE_AGENT) + 1u;
    if (arrived == phase * 16u){
      __hip_atomic_store(gen, phase, __ATOMIC_RELEASE, __HIP_MEMORY_SCOPE_AGENT);
    } else {
      unsigned spins = 0;
      while (__hip_atomic_load(gen, __ATOMIC_RELAXED, __HIP_MEMORY_SCOPE_AGENT) < phase){
        __builtin_amdgcn_s_sleep(2);
        if (++spins > (1u << 22)) break;   // failsafe against hard hang
      }
      (void)__hip_atomic_load(gen, __ATOMIC_ACQUIRE, __HIP_MEMORY_SCOPE_AGENT);
    }
  }
  __syncthreads();
}

// A-frags from global h (bf16 [4096][256]); B-frags from LDS slice; acc +=.
// kk-outer chunking keeps live regs modest (no spills).
__device__ inline void gemm_k256(f32x4 acc[4][4],
                                 const unsigned short* __restrict__ hbuf,
                                 int wrow0,
                                 const unsigned short* __restrict__ wl,
                                 int lane){
  const int lr = lane & 15, lg = lane >> 4;
  #pragma unroll
  for (int kp = 0; kp < 4; ++kp){
    bf16x8 A2[4][2], B2[4][2];
    #pragma unroll
    for (int mt = 0; mt < 4; ++mt){
      const unsigned short* rp = hbuf + (size_t)(wrow0 + mt * 16 + lr) * 256 + kp * 64 + lg * 8;
      A2[mt][0] = *reinterpret_cast<const bf16x8*>(rp);
      A2[mt][1] = *reinterpret_cast<const bf16x8*>(rp + 32);
    }
    #pragma unroll
    for (int gt = 0; gt < 4; ++gt){
      #pragma unroll
      for (int q = 0; q < 2; ++q)
        B2[gt][q] = *reinterpret_cast<const bf16x8*>(wl + ((size_t)(gt * 8 + kp * 2 + q) * 64 + lane) * 8);
    }
    #pragma unroll
    for (int mt = 0; mt < 4; ++mt)
      #pragma unroll
      for (int gt = 0; gt < 4; ++gt){
        f32x4 c = __builtin_amdgcn_mfma_f32_16x16x32_bf16(A2[mt][0], B2[gt][0], acc[mt][gt], 0, 0, 0);
        acc[mt][gt] = __builtin_amdgcn_mfma_f32_16x16x32_bf16(A2[mt][1], B2[gt][1], c, 0, 0, 0);
      }
  }
}

__device__ inline void cell_upd(f32x4 acc[4][4], float cst[4][4],
                                unsigned short* __restrict__ hbuf,
                                int wrow0, int U0, int lane){
  const int lr = lane & 15, lg = lane >> 4;
  #pragma unroll
  for (int mt = 0; mt < 4; ++mt){
    #pragma unroll
    for (int r = 0; r < 4; ++r){
      const float gi = acc[mt][0][r], gf = acc[mt][1][r];
      const float gg = acc[mt][2][r], go = acc[mt][3][r];
      float c = sigm(gf) * cst[mt][r] + sigm(gi) * tanh_(gg);
      cst[mt][r] = c;
      hbuf[(size_t)(wrow0 + mt * 16 + lg * 4 + r) * 256 + U0 + lr] = f2bf_u(sigm(go) * tanh_(c));
    }
  }
}

__device__ inline void init_bias(f32x4 acc[4][4], const float* __restrict__ b, int U0, int lr){
  #pragma unroll
  for (int gt = 0; gt < 4; ++gt){
    const float bb = b[gt * 256 + U0 + lr];
    #pragma unroll
    for (int mt = 0; mt < 4; ++mt) acc[mt][gt] = (f32x4){bb, bb, bb, bb};
  }
}

__global__ __launch_bounds__(256, 1) void lstm_main(MainArgs a){
  __shared__ unsigned short wlds[3][SLICE_SH];  // 96 KB
  __shared__ float pin[256][2];
  __shared__ float hw[512];
  __shared__ float cw[768];

  const int tid = threadIdx.x, wave = tid >> 6, lane = tid & 63;
  const int lr = lane & 15, lg = lane >> 4;
  const int xcd = blockIdx.x & 7, idx = blockIdx.x >> 3;
  const int bg = xcd * 2 + (idx >> 4), ug = idx & 15;
  const int B0 = bg * 256, U0 = ug * 16;
  const int wrow0 = B0 + wave * 64;

  unsigned* bcnt = a.bars + bg * 32;
  unsigned* bgen = bcnt + 1;
  unsigned phase = 0;

  unsigned short* hp0[2] = { a.hb,                   a.hb + HBUF_SHORTS };
  unsigned short* hp1[2] = { a.hb + 2 * HBUF_SHORTS, a.hb + 3 * HBUF_SHORTS };
  unsigned short* henc0  =   a.hb + 4 * HBUF_SHORTS;
  unsigned short* henc1  =   a.hb + 5 * HBUF_SHORTS;

  // ---- prologue phase: zero h(-1) slices, stage encoder weights, conf W ----
  {
    const size_t o = (size_t)(B0 + tid) * 256 + U0;
    const uint4 z = {0, 0, 0, 0};
    *(uint4*)(hp0[0] + o) = z; *(uint4*)(hp0[0] + o + 8) = z;
    *(uint4*)(hp1[0] + o) = z; *(uint4*)(hp1[0] + o + 8) = z;
  }
  for (int i = tid; i < 768; i += 256) cw[i] = a.confW[i];
  for (int s = 0; s < 3; ++s){
    const uint4* src = (const uint4*)(a.wpack + (size_t)(s * 16 + ug) * SLICE_SH);
    uint4* dst = (uint4*)wlds[s];
    for (int i = tid; i < 2048; i += 256) dst[i] = src[i];
  }
  bg_barrier(bcnt, bgen, ++phase);

  float c0[4][4] = {}, c1[4][4] = {};
  const float* bias0 = a.bias;
  const float* bias1 = a.bias + 1024;

  // ---------------- encoder, skewed: 51 phases ----------------
  // phase s: L0(t=s) [s<50] and L1(t=s-1) [s>=1].
  // h0(t) lives in hp0[(t+1)&1]; h1(t) lives in hp1[(t+1)&1].
  for (int s = 0; s <= 50; ++s){
    if (s < 50){
      f32x4 acc[4][4];
      float4 w4[4];
      init_bias(acc, bias0, U0, lr);
      #pragma unroll
      for (int gt = 0; gt < 4; ++gt)
        w4[gt] = *(const float4*)(a.encWih0 + (size_t)(gt * 256 + U0 + lr) * 4);
      #pragma unroll
      for (int mt = 0; mt < 4; ++mt){
        #pragma unroll
        for (int r = 0; r < 4; ++r){
          const float4 xv = *(const float4*)(a.x + (size_t)(wrow0 + mt * 16 + lg * 4 + r) * 200 + s * 4);
          #pragma unroll
          for (int gt = 0; gt < 4; ++gt)
            acc[mt][gt][r] += xv.x * w4[gt].x + xv.y * w4[gt].y + xv.z * w4[gt].z + xv.w * w4[gt].w;
        }
      }
      gemm_k256(acc, hp0[s & 1], wrow0, wlds[0], lane);   // Whh0 @ h0(s-1)
      cell_upd(acc, c0, hp0[(s + 1) & 1], wrow0, U0, lane);
    }
    if (s >= 1){
      f32x4 acc[4][4];
      init_bias(acc, bias1, U0, lr);
      gemm_k256(acc, hp0[s & 1], wrow0, wlds[1], lane);        // Wih1 @ h0(s-1)
      gemm_k256(acc, hp1[(s - 1) & 1], wrow0, wlds[2], lane);  // Whh1 @ h1(s-2)
      cell_upd(acc, c1, hp1[s & 1], wrow0, U0, lane);
    }
    bg_barrier(bcnt, bgen, ++phase);
  }
  // encoder finals: h0(49) in hp0[0], h1(49) in hp1[0]

  // ---- post-encoder phase: conf head, save henc + c, stage k=0 weights ----
  {
    const int row = B0 + tid;
    if (ug == 0){
      const bf16x8* rp = (const bf16x8*)(hp1[0] + (size_t)row * 256);
      float l0 = a.confB[0], l1 = a.confB[1], l2 = a.confB[2];
      for (int ch = 0; ch < 32; ++ch){
        const bf16x8 v = rp[ch];
        #pragma unroll
        for (int j = 0; j < 8; ++j){
          const float f = (float)v[j];
          l0 += f * cw[ch * 8 + j];
          l1 += f * cw[256 + ch * 8 + j];
          l2 += f * cw[512 + ch * 8 + j];
        }
      }
      const float mx = fmaxf(l0, fmaxf(l1, l2));
      const float e0 = __expf(l0 - mx), e1 = __expf(l1 - mx), e2 = __expf(l2 - mx);
      const float inv = 1.f / (e0 + e1 + e2);
      a.out[147456 + (size_t)row * 3 + 0] = e0 * inv;
      a.out[147456 + (size_t)row * 3 + 1] = e1 * inv;
      a.out[147456 + (size_t)row * 3 + 2] = e2 * inv;
    }
    const size_t o = (size_t)row * 256 + U0;
    *(uint4*)(henc0 + o)     = *(const uint4*)(hp0[0] + o);
    *(uint4*)(henc0 + o + 8) = *(const uint4*)(hp0[0] + o + 8);
    *(uint4*)(henc1 + o)     = *(const uint4*)(hp1[0] + o);
    *(uint4*)(henc1 + o + 8) = *(const uint4*)(hp1[0] + o + 8);
    // stage k=0 decoder weights + head row, init pin from x[:, -1, :2]
    for (int s = 0; s < 3; ++s){
      const int mi = 3 * s + 3;  // mats 3,6,9 (+k later); k=0 here
      const uint4* src = (const uint4*)(a.wpack + (size_t)(mi * 16 + ug) * SLICE_SH);
      uint4* dst = (uint4*)wlds[s];
      for (int i = tid; i < 2048; i += 256) dst[i] = src[i];
    }
    for (int i = tid; i < 512; i += 256) hw[i] = a.headW[i];
    pin[tid][0] = a.x[(size_t)row * 200 + 196];
    pin[tid][1] = a.x[(size_t)row * 200 + 197];
  }
  float c0s[4][4], c1s[4][4];
  #pragma unroll
  for (int mt = 0; mt < 4; ++mt)
    #pragma unroll
    for (int r = 0; r < 4; ++r){ c0s[mt][r] = c0[mt][r]; c1s[mt][r] = c1[mt][r]; }
  bg_barrier(bcnt, bgen, ++phase);

  // ---------------- decoders: 3 sequential passes, skewed ----------------
  // dec h0(t) in hp0[(t+1)&1], h1(t) in hp1[(t+1)&1]; h(-1) in hp*[0].
  for (int k = 0; k < 3; ++k){
    const float* db0 = a.bias + (size_t)(2 + k) * 1024;
    const float* db1 = a.bias + (size_t)(5 + k) * 1024;
    const float hb0 = a.headB[k * 2], hb1 = a.headB[k * 2 + 1];

    if (k > 0){
      // restore phase: henc -> hp*[0] (own slice), c regs, weights, pin
      const size_t o = (size_t)(B0 + tid) * 256 + U0;
      *(uint4*)(hp0[0] + o)     = *(const uint4*)(henc0 + o);
      *(uint4*)(hp0[0] + o + 8) = *(const uint4*)(henc0 + o + 8);
      *(uint4*)(hp1[0] + o)     = *(const uint4*)(henc1 + o);
      *(uint4*)(hp1[0] + o + 8) = *(const uint4*)(henc1 + o + 8);
      const int m3[3] = {3 + k, 6 + k, 9 + k};
      for (int s = 0; s < 3; ++s){
        const uint4* src = (const uint4*)(a.wpack + (size_t)(m3[s] * 16 + ug) * SLICE_SH);
        uint4* dst = (uint4*)wlds[s];
        for (int i = tid; i < 2048; i += 256) dst[i] = src[i];
      }
      for (int i = tid; i < 512; i += 256) hw[i] = a.headW[(size_t)k * 512 + i];
      pin[tid][0] = a.x[(size_t)(B0 + tid) * 200 + 196];
      pin[tid][1] = a.x[(size_t)(B0 + tid) * 200 + 197];
      #pragma unroll
      for (int mt = 0; mt < 4; ++mt)
        #pragma unroll
        for (int r = 0; r < 4; ++r){ c0[mt][r] = c0s[mt][r]; c1[mt][r] = c1s[mt][r]; }
      bg_barrier(bcnt, bgen, ++phase);
    }

    // macro-ish lambdas for the two layer computations
    auto do_L0 = [&](int t){
      f32x4 acc[4][4];
      float2 w2[4];
      init_bias(acc, db0, U0, lr);
      #pragma unroll
      for (int gt = 0; gt < 4; ++gt)
        w2[gt] = *(const float2*)(a.decWih0 + (size_t)k * 2048 + (size_t)(gt * 256 + U0 + lr) * 2);
      #pragma unroll
      for (int mt = 0; mt < 4; ++mt){
        #pragma unroll
        for (int r = 0; r < 4; ++r){
          const int li = wave * 64 + mt * 16 + lg * 4 + r;
          const float p0 = pin[li][0], p1 = pin[li][1];
          #pragma unroll
          for (int gt = 0; gt < 4; ++gt)
            acc[mt][gt][r] += p0 * w2[gt].x + p1 * w2[gt].y;
        }
      }
      gemm_k256(acc, hp0[t & 1], wrow0, wlds[0], lane);      // Whh0 @ h0(t-1)
      cell_upd(acc, c0, hp0[(t + 1) & 1], wrow0, U0, lane);
    };
    auto do_L1 = [&](int t){
      f32x4 acc[4][4];
      init_bias(acc, db1, U0, lr);
      gemm_k256(acc, hp0[(t + 1) & 1], wrow0, wlds[1], lane); // Wih1 @ h0(t)
      gemm_k256(acc, hp1[t & 1], wrow0, wlds[2], lane);       // Whh1 @ h1(t-1)
      cell_upd(acc, c1, hp1[(t + 1) & 1], wrow0, U0, lane);
    };
    auto do_pred = [&](int t){  // reads h1(t) = hp1[(t+1)&1]; fills pin; ug0 writes out
      const int row = B0 + tid;
      const bf16x8* rp = (const bf16x8*)(hp1[(t + 1) & 1] + (size_t)row * 256);
      float s0 = hb0, s1 = hb1;
      for (int ch = 0; ch < 32; ++ch){
        const bf16x8 v = rp[ch];
        #pragma unroll
        for (int j = 0; j < 8; ++j){
          const float f = (float)v[j];
          s0 += f * hw[ch * 8 + j];
          s1 += f * hw[256 + ch * 8 + j];
        }
      }
      pin[tid][0] = s0; pin[tid][1] = s1;
      if (ug == 0){
        const size_t ob = (((size_t)row * 3 + k) * 6 + t) * 2;
        a.out[ob] = s0; a.out[ob + 1] = s1;
      }
    };

    do_L0(0);                       // phase: L0(0)
    bg_barrier(bcnt, bgen, ++phase);
    do_L1(0);                       // phase: L1(0)
    bg_barrier(bcnt, bgen, ++phase);
    for (int t = 1; t < 6; ++t){
      do_pred(t - 1);               // phase: pred(t-1) + L0(t)
      __syncthreads();              // pin visible block-locally before L0 reads
      do_L0(t);
      bg_barrier(bcnt, bgen, ++phase);
      do_L1(t);                     // phase: L1(t)
      bg_barrier(bcnt, bgen, ++phase);
    }
    do_pred(5);                     // phase: final pred(5) (out write only)
    bg_barrier(bcnt, bgen, ++phase);
  }
}

extern "C" void kernel_launch(void* const* d_in, const int* in_sizes, int n_in,
                              void* d_out, int out_size, void* d_ws, size_t ws_size,
                              hipStream_t stream){
  PrepArgs pa;
  pa.mats[0] = (const float*)d_in[2];   // enc_Whh0
  pa.mats[1] = (const float*)d_in[5];   // enc_Wih1
  pa.mats[2] = (const float*)d_in[6];   // enc_Whh1
  for (int k = 0; k < 3; ++k){
    pa.mats[3 + k] = (const float*)d_in[10] + (size_t)k * 262144;  // dec_Whh0[k]
    pa.mats[6 + k] = (const float*)d_in[13] + (size_t)k * 262144;  // dec_Wih1[k]
    pa.mats[9 + k] = (const float*)d_in[14] + (size_t)k * 262144;  // dec_Whh1[k]
  }
  pa.ba[0] = (const float*)d_in[3];  pa.bb[0] = (const float*)d_in[4];
  pa.ba[1] = (const float*)d_in[7];  pa.bb[1] = (const float*)d_in[8];
  for (int k = 0; k < 3; ++k){
    pa.ba[2 + k] = (const float*)d_in[11] + (size_t)k * 1024;
    pa.bb[2 + k] = (const float*)d_in[12] + (size_t)k * 1024;
    pa.ba[5 + k] = (const float*)d_in[15] + (size_t)k * 1024;
    pa.bb[5 + k] = (const float*)d_in[16] + (size_t)k * 1024;
  }
  pa.wp   = (unsigned short*)d_ws;
  pa.bias = (float*)((char*)d_ws + BIAS_OFF_BYTES);
  pa.bars = (unsigned*)((char*)d_ws + BAR_OFF_BYTES);

  prep_kernel<<<12324, 256, 0, stream>>>(pa);

  MainArgs ma;
  ma.x       = (const float*)d_in[0];
  ma.encWih0 = (const float*)d_in[1];
  ma.decWih0 = (const float*)d_in[9];
  ma.headW   = (const float*)d_in[17];
  ma.headB   = (const float*)d_in[18];
  ma.confW   = (const float*)d_in[19];
  ma.confB   = (const float*)d_in[20];
  ma.wpack   = (const unsigned short*)d_ws;
  ma.bias    = (const float*)((char*)d_ws + BIAS_OFF_BYTES);
  ma.bars    = (unsigned*)((char*)d_ws + BAR_OFF_BYTES);
  ma.hb      = (unsigned short*)((char*)d_ws + H_OFF_BYTES);
  ma.out     = (float*)d_out;

  lstm_main<<<256, 256, 0, stream>>>(ma);
}